// Round 5
// baseline (899.368 us; speedup 1.0000x reference)
//
#include <hip/hip_runtime.h>

#define NN 100000
#define NE 1600000
#define DD 64
#define NBUK 782            // ceil(NN/128): 128-node buckets
#define GEMM_BLOCKS 6250    // NN/16
#define HIST_BLOCKS 125     // NE/12800
#define PLACE_EPB 8192      // edges per place block (32/thread)
#define PLACE_BLOCKS 196    // ceil(NE/8192)

// ---------------- K1: fused  support = x@W  +  782-bucket dst histogram ----------------
__global__ __launch_bounds__(256) void k_gemm_hist(const float* __restrict__ x,
                                                   const float* __restrict__ Wg,
                                                   float* __restrict__ support,
                                                   const int* __restrict__ edst,
                                                   int* __restrict__ cnt) {
    if (blockIdx.x >= GEMM_BLOCKS) {
        __shared__ int h[NBUK];
        for (int i = threadIdx.x; i < NBUK; i += 256) h[i] = 0;
        __syncthreads();
        const int base = (blockIdx.x - GEMM_BLOCKS) * 12800;
#pragma unroll 5
        for (int k = 0; k < 50; ++k)
            atomicAdd(&h[edst[base + k * 256 + threadIdx.x] >> 7], 1);
        __syncthreads();
        for (int i = threadIdx.x; i < NBUK; i += 256)
            if (h[i]) atomicAdd(&cnt[i], h[i]);
        return;
    }
    __shared__ float Ws[DD * DD];
    for (int i = threadIdx.x; i < DD * DD; i += 256)
        Ws[i] = Wg[i];
    __syncthreads();

    const int wave = threadIdx.x >> 6, lane = threadIdx.x & 63;
    const size_t row0 = (size_t)blockIdx.x * 16 + (size_t)wave * 4;
    const float* xr = x + row0 * DD;

    float acc0 = 0.f, acc1 = 0.f, acc2 = 0.f, acc3 = 0.f;
#pragma unroll
    for (int k = 0; k < DD; k += 4) {
        float4 p0 = *(const float4*)(xr + 0 * DD + k);
        float4 p1 = *(const float4*)(xr + 1 * DD + k);
        float4 p2 = *(const float4*)(xr + 2 * DD + k);
        float4 p3 = *(const float4*)(xr + 3 * DD + k);
        float w0 = Ws[(k + 0) * DD + lane];
        float w1 = Ws[(k + 1) * DD + lane];
        float w2 = Ws[(k + 2) * DD + lane];
        float w3 = Ws[(k + 3) * DD + lane];
        acc0 = fmaf(p0.x, w0, acc0); acc0 = fmaf(p0.y, w1, acc0);
        acc0 = fmaf(p0.z, w2, acc0); acc0 = fmaf(p0.w, w3, acc0);
        acc1 = fmaf(p1.x, w0, acc1); acc1 = fmaf(p1.y, w1, acc1);
        acc1 = fmaf(p1.z, w2, acc1); acc1 = fmaf(p1.w, w3, acc1);
        acc2 = fmaf(p2.x, w0, acc2); acc2 = fmaf(p2.y, w1, acc2);
        acc2 = fmaf(p2.z, w2, acc2); acc2 = fmaf(p2.w, w3, acc2);
        acc3 = fmaf(p3.x, w0, acc3); acc3 = fmaf(p3.y, w1, acc3);
        acc3 = fmaf(p3.z, w2, acc3); acc3 = fmaf(p3.w, w3, acc3);
    }
    float* sp = support + row0 * DD + lane;
    sp[0 * DD] = acc0; sp[1 * DD] = acc1; sp[2 * DD] = acc2; sp[3 * DD] = acc3;
}

// ---------------- K2: exclusive scan of 782 bucket counts (one block) ----------------
__global__ __launch_bounds__(256) void k_scan(const int* __restrict__ cnt,
                                              int* __restrict__ bstart,
                                              int* __restrict__ tail) {
    __shared__ int sc[256];
    const int t = threadIdx.x;
    int c[4], ts = 0;
#pragma unroll
    for (int j = 0; j < 4; ++j) {
        int i = t * 4 + j;
        c[j] = (i < NBUK) ? cnt[i] : 0;
        ts += c[j];
    }
    sc[t] = ts; __syncthreads();
    for (int o = 1; o < 256; o <<= 1) {
        int u = (t >= o) ? sc[t - o] : 0;
        __syncthreads();
        sc[t] += u;
        __syncthreads();
    }
    int run = sc[t] - ts;
#pragma unroll
    for (int j = 0; j < 4; ++j) {
        int i = t * 4 + j;
        if (i < NBUK) { bstart[i] = run; tail[i] = run; run += c[j]; }
    }
    if (t == 255) bstart[NBUK] = NE;
}

// ---------------- K3: place edges into bucket-grouped perm[] in contiguous chunks ----------------
__global__ __launch_bounds__(256) void k_place(const int* __restrict__ esrc,
                                               const int* __restrict__ edst,
                                               const float* __restrict__ ew,
                                               int* __restrict__ tail,
                                               int2* __restrict__ perm) {
    __shared__ int lcnt[NBUK], loff[NBUK];
    for (int i = threadIdx.x; i < NBUK; i += 256) lcnt[i] = 0;
    __syncthreads();
    const int e0 = blockIdx.x * PLACE_EPB;
#pragma unroll 4
    for (int k = 0; k < 32; ++k) {
        int e = e0 + k * 256 + threadIdx.x;
        if (e < NE) atomicAdd(&lcnt[edst[e] >> 7], 1);
    }
    __syncthreads();
    for (int i = threadIdx.x; i < NBUK; i += 256) {
        int c = lcnt[i];
        loff[i] = c ? atomicAdd(&tail[i], c) : 0;
    }
    __syncthreads();
#pragma unroll 4
    for (int k = 0; k < 32; ++k) {
        int e = e0 + k * 256 + threadIdx.x;
        if (e < NE) {
            int d = edst[e];
            int p = atomicAdd(&loff[d >> 7], 1);
            perm[p] = make_int2(esrc[e] | ((d & 127) << 24), __float_as_int(ew[e]));
        }
    }
}

// ---------------- K4: per-bucket gather in LDS + fused column stats ----------------
__global__ __launch_bounds__(512) void k_gather(const int* __restrict__ bstart,
                                                const int2* __restrict__ perm,
                                                const float* __restrict__ support,
                                                float* __restrict__ out,
                                                float* __restrict__ stats) {
    __shared__ float lagg[128 * DD];   // 32 KB
    const int t = threadIdx.x, wave = t >> 6, lane = t & 63;
#pragma unroll
    for (int i = 0; i < 4; ++i)
        *(float4*)&lagg[(t + i * 512) * 4] = make_float4(0.f, 0.f, 0.f, 0.f);
    __syncthreads();

    const int bs = bstart[blockIdx.x], be = bstart[blockIdx.x + 1];
    int j = bs + wave;
    for (; j + 24 < be; j += 32) {
        int2 r0 = perm[j], r1 = perm[j + 8], r2 = perm[j + 16], r3 = perm[j + 24];
        float v0 = support[(size_t)(r0.x & 0xFFFFFF) * DD + lane];
        float v1 = support[(size_t)(r1.x & 0xFFFFFF) * DD + lane];
        float v2 = support[(size_t)(r2.x & 0xFFFFFF) * DD + lane];
        float v3 = support[(size_t)(r3.x & 0xFFFFFF) * DD + lane];
        atomicAdd(&lagg[(((unsigned)r0.x >> 24) & 127) * DD + lane], __int_as_float(r0.y) * v0);
        atomicAdd(&lagg[(((unsigned)r1.x >> 24) & 127) * DD + lane], __int_as_float(r1.y) * v1);
        atomicAdd(&lagg[(((unsigned)r2.x >> 24) & 127) * DD + lane], __int_as_float(r2.y) * v2);
        atomicAdd(&lagg[(((unsigned)r3.x >> 24) & 127) * DD + lane], __int_as_float(r3.y) * v3);
    }
    for (; j < be; j += 8) {
        int2 r = perm[j];
        float v = support[(size_t)(r.x & 0xFFFFFF) * DD + lane];
        atomicAdd(&lagg[(((unsigned)r.x >> 24) & 127) * DD + lane], __int_as_float(r.y) * v);
    }
    __syncthreads();

    const int node0 = blockIdx.x * 128;
    for (int r = wave; r < 128; r += 8)
        if (node0 + r < NN)
            out[(size_t)(node0 + r) * DD + lane] = lagg[r * DD + lane];

    // fused column stats: 8 row-groups of 16 rows; zero rows (past NN) contribute 0
    float s = 0.f, sq = 0.f;
    for (int r = wave * 16; r < wave * 16 + 16; ++r) {
        float v = lagg[r * DD + lane];
        s += v; sq = fmaf(v, v, sq);
    }
    __syncthreads();
    float* red = lagg;                 // overlay first 1024 floats
    red[wave * DD + lane] = s;
    red[512 + wave * DD + lane] = sq;
    __syncthreads();
    if (t < DD) {
        float ts = 0.f, tq = 0.f;
#pragma unroll
        for (int g = 0; g < 8; ++g) { ts += red[g * DD + t]; tq += red[512 + g * DD + t]; }
        atomicAdd(&stats[t], ts);
        atomicAdd(&stats[DD + t], tq);
    }
}

// ---------------- K5: fold stats into scale/shift ----------------
__global__ void k_finstats(const float* __restrict__ sums, float* __restrict__ ss,
                           const float* __restrict__ gamma,
                           const float* __restrict__ beta) {
    const int c = threadIdx.x;
    const float invn = 1.0f / NN;
    float mean = sums[c] * invn;
    float var = fmaxf(sums[DD + c] * invn - mean * mean, 0.f);
    float sc = rsqrtf(var + 1e-5f) * gamma[c];
    ss[c] = sc;
    ss[DD + c] = beta[c] - mean * sc;
}

// ---------------- K6: out = relu(out*scale + shift) in-place ----------------
__global__ __launch_bounds__(256) void k_final(float* __restrict__ out,
                                               const float* __restrict__ ss) {
    const size_t idx = ((size_t)blockIdx.x * 256 + threadIdx.x) * 4;
    const int c = (int)(idx & 63);
    float4 v = *(const float4*)(out + idx);
    float4 o;
    o.x = fmaxf(fmaf(v.x, ss[c + 0], ss[DD + c + 0]), 0.f);
    o.y = fmaxf(fmaf(v.y, ss[c + 1], ss[DD + c + 1]), 0.f);
    o.z = fmaxf(fmaf(v.z, ss[c + 2], ss[DD + c + 2]), 0.f);
    o.w = fmaxf(fmaf(v.w, ss[c + 3], ss[DD + c + 3]), 0.f);
    *(float4*)(out + idx) = o;
}

extern "C" void kernel_launch(void* const* d_in, const int* in_sizes, int n_in,
                              void* d_out, int out_size, void* d_ws, size_t ws_size,
                              hipStream_t stream) {
    const float* x     = (const float*)d_in[0];
    const int*   esrc  = (const int*)d_in[1];
    const int*   edst  = (const int*)d_in[2];
    const float* ew    = (const float*)d_in[3];
    const float* W     = (const float*)d_in[4];
    // d_in[5] = bias: cancels exactly in batchnorm (shift-invariant) — unused.
    const float* gamma = (const float*)d_in[6];
    const float* beta  = (const float*)d_in[7];
    float*       out   = (float*)d_out;   // doubles as the agg buffer

    char* ws = (char*)d_ws;
    float* support = (float*)ws;   ws += (size_t)NN * DD * 4;   // 25.6 MB
    int2*  perm    = (int2*)ws;    ws += (size_t)NE * 8;        // 12.8 MB
    int*   cnt     = (int*)ws;     ws += NBUK * 4;              // 782 bucket counts
    float* stats   = (float*)ws;   ws += 256 * 4;               // sum|sumsq|scale|shift
    int*   bstart  = (int*)ws;     ws += (NBUK + 1) * 4;
    int*   tail    = (int*)ws;

    // zero cnt + stats (adjacent, ~4 KB)
    hipMemsetAsync(cnt, 0, NBUK * 4 + 256 * 4, stream);

    k_gemm_hist<<<GEMM_BLOCKS + HIST_BLOCKS, 256, 0, stream>>>(x, W, support, edst, cnt);
    k_scan     <<<1, 256, 0, stream>>>(cnt, bstart, tail);
    k_place    <<<PLACE_BLOCKS, 256, 0, stream>>>(esrc, edst, ew, tail, perm);
    k_gather   <<<NBUK, 512, 0, stream>>>(bstart, perm, support, out, stats);
    k_finstats <<<1, 64, 0, stream>>>(stats, stats + 2 * DD, gamma, beta);
    k_final    <<<NN * DD / 4 / 256, 256, 0, stream>>>(out, stats + 2 * DD);
}

// Round 6
// 789.153 us; speedup vs baseline: 1.1397x; 1.1397x over previous
//
#include <hip/hip_runtime.h>
#include <hip/hip_bf16.h>

#define NN 100000
#define NE 1600000
#define DD 64
#define NCOARSE 98          // 1024-node coarse buckets (node>>10)
#define NFINE 3125          // 32-node fine buckets (node>>5); 3125*32 == 100000 exactly
#define GEMM_BLOCKS 6250    // NN/16
#define HIST_BLOCKS 125     // NE/12800
#define PLACE_EPB 8192
#define PLACE_BLOCKS 196    // ceil(NE/8192)

__device__ inline float bfu(unsigned short u) { return __uint_as_float((unsigned)u << 16); }
__device__ inline unsigned short f2bf(float f) {
    __hip_bfloat16 h = __float2bfloat16(f);
    unsigned short s; __builtin_memcpy(&s, &h, 2); return s;
}

// ---------------- K1: fused  support_bf16 = x@W  +  coarse dst histogram ----------------
__global__ __launch_bounds__(256) void k_gemm_hist(const float* __restrict__ x,
                                                   const float* __restrict__ Wg,
                                                   unsigned short* __restrict__ support,
                                                   const int* __restrict__ edst,
                                                   int* __restrict__ cnt98) {
    if (blockIdx.x >= GEMM_BLOCKS) {
        __shared__ int h[NCOARSE];
        for (int i = threadIdx.x; i < NCOARSE; i += 256) h[i] = 0;
        __syncthreads();
        const int base = (blockIdx.x - GEMM_BLOCKS) * 12800;
#pragma unroll 5
        for (int k = 0; k < 50; ++k)
            atomicAdd(&h[edst[base + k * 256 + threadIdx.x] >> 10], 1);
        __syncthreads();
        for (int i = threadIdx.x; i < NCOARSE; i += 256)
            if (h[i]) atomicAdd(&cnt98[i], h[i]);
        return;
    }
    __shared__ float Ws[DD * DD];
    for (int i = threadIdx.x; i < DD * DD; i += 256)
        Ws[i] = Wg[i];
    __syncthreads();

    const int wave = threadIdx.x >> 6, lane = threadIdx.x & 63;
    const size_t row0 = (size_t)blockIdx.x * 16 + (size_t)wave * 4;
    const float* xr = x + row0 * DD;

    float acc0 = 0.f, acc1 = 0.f, acc2 = 0.f, acc3 = 0.f;
#pragma unroll
    for (int k = 0; k < DD; k += 4) {
        float4 p0 = *(const float4*)(xr + 0 * DD + k);
        float4 p1 = *(const float4*)(xr + 1 * DD + k);
        float4 p2 = *(const float4*)(xr + 2 * DD + k);
        float4 p3 = *(const float4*)(xr + 3 * DD + k);
        float w0 = Ws[(k + 0) * DD + lane];
        float w1 = Ws[(k + 1) * DD + lane];
        float w2 = Ws[(k + 2) * DD + lane];
        float w3 = Ws[(k + 3) * DD + lane];
        acc0 = fmaf(p0.x, w0, acc0); acc0 = fmaf(p0.y, w1, acc0);
        acc0 = fmaf(p0.z, w2, acc0); acc0 = fmaf(p0.w, w3, acc0);
        acc1 = fmaf(p1.x, w0, acc1); acc1 = fmaf(p1.y, w1, acc1);
        acc1 = fmaf(p1.z, w2, acc1); acc1 = fmaf(p1.w, w3, acc1);
        acc2 = fmaf(p2.x, w0, acc2); acc2 = fmaf(p2.y, w1, acc2);
        acc2 = fmaf(p2.z, w2, acc2); acc2 = fmaf(p2.w, w3, acc2);
        acc3 = fmaf(p3.x, w0, acc3); acc3 = fmaf(p3.y, w1, acc3);
        acc3 = fmaf(p3.z, w2, acc3); acc3 = fmaf(p3.w, w3, acc3);
    }
    unsigned short* sp = support + row0 * DD + lane;
    sp[0 * DD] = f2bf(acc0); sp[1 * DD] = f2bf(acc1);
    sp[2 * DD] = f2bf(acc2); sp[3 * DD] = f2bf(acc3);
}

// ---------------- K2: exclusive scan of 98 coarse counts ----------------
__global__ __launch_bounds__(128) void k_scan98(const int* __restrict__ cnt98,
                                                int* __restrict__ cstart,
                                                int* __restrict__ ctail,
                                                int* __restrict__ bstart) {
    __shared__ int sc[128];
    const int t = threadIdx.x;
    const int v = (t < NCOARSE) ? cnt98[t] : 0;
    sc[t] = v; __syncthreads();
    for (int o = 1; o < 128; o <<= 1) {
        int u = (t >= o) ? sc[t - o] : 0;
        __syncthreads();
        sc[t] += u;
        __syncthreads();
    }
    if (t < NCOARSE) { cstart[t] = sc[t] - v; ctail[t] = sc[t] - v; }
    if (t == 0) { cstart[NCOARSE] = NE; bstart[NFINE] = NE; }
}

// ---------------- K3: placeA — group edges by coarse bucket (668 B avg chunks) ----------------
// permA.x = src | (dlocal<<20)  where dlocal = d & 1023 (10 bits);  permA.y = weight bits
__global__ __launch_bounds__(256) void k_placeA(const int* __restrict__ esrc,
                                                const int* __restrict__ edst,
                                                const float* __restrict__ ew,
                                                int* __restrict__ ctail,
                                                int2* __restrict__ permA) {
    __shared__ int lcnt[NCOARSE], loff[NCOARSE];
    for (int i = threadIdx.x; i < NCOARSE; i += 256) lcnt[i] = 0;
    __syncthreads();
    const int e0 = blockIdx.x * PLACE_EPB;
#pragma unroll 4
    for (int k = 0; k < 32; ++k) {
        int e = e0 + k * 256 + threadIdx.x;
        if (e < NE) atomicAdd(&lcnt[edst[e] >> 10], 1);
    }
    __syncthreads();
    for (int i = threadIdx.x; i < NCOARSE; i += 256) {
        int c = lcnt[i];
        loff[i] = c ? atomicAdd(&ctail[i], c) : 0;
    }
    __syncthreads();
#pragma unroll 4
    for (int k = 0; k < 32; ++k) {
        int e = e0 + k * 256 + threadIdx.x;
        if (e < NE) {
            int d = edst[e];
            int p = atomicAdd(&loff[d >> 10], 1);
            permA[p] = make_int2(esrc[e] | ((d & 1023) << 20), __float_as_int(ew[e]));
        }
    }
}

// ---------------- K4: placeB — one block per coarse bucket; distribute into 32 fine buckets ----------------
// perm.x = src | (row<<20)  where row = d & 31 (5 bits);  writes bstart[] for its fine buckets
__global__ __launch_bounds__(512) void k_placeB(const int* __restrict__ cstart,
                                                const int2* __restrict__ permA,
                                                int2* __restrict__ perm,
                                                int* __restrict__ bstart) {
    __shared__ int lcnt[32], lstart[32], loff[32];
    const int c = blockIdx.x, t = threadIdx.x;
    const int cs = cstart[c], ce = cstart[c + 1];
    if (t < 32) lcnt[t] = 0;
    __syncthreads();
    for (int j = cs + t; j < ce; j += 512)
        atomicAdd(&lcnt[(permA[j].x >> 25) & 31], 1);
    __syncthreads();
    if (t == 0) {
        int run = cs;
        for (int k = 0; k < 32; ++k) { lstart[k] = run; loff[k] = run; run += lcnt[k]; }
    }
    __syncthreads();
    if (t < 32) {
        int f = c * 32 + t;
        if (f < NFINE) bstart[f] = lstart[t];
    }
    for (int j = cs + t; j < ce; j += 512) {
        int2 m = permA[j];
        int fl = (m.x >> 25) & 31;
        int p = atomicAdd(&loff[fl], 1);
        perm[p] = make_int2((m.x & 0xFFFFF) | (((m.x >> 20) & 31) << 20), m.y);
    }
}

// ---------------- K5: gather — one block per 32-node fine bucket, 8 KB LDS tile, fused stats ----------------
__global__ __launch_bounds__(256) void k_gather(const int* __restrict__ bstart,
                                                const int2* __restrict__ perm,
                                                const unsigned short* __restrict__ support,
                                                float* __restrict__ out,
                                                float* __restrict__ stats) {
    __shared__ float lagg[32 * DD];   // 8 KB
    const int t = threadIdx.x, wave = t >> 6, lane = t & 63;
    *(float4*)&lagg[t * 8]     = make_float4(0.f, 0.f, 0.f, 0.f);
    *(float4*)&lagg[t * 8 + 4] = make_float4(0.f, 0.f, 0.f, 0.f);
    __syncthreads();

    const int bs = bstart[blockIdx.x], be = bstart[blockIdx.x + 1];
    int j = bs + wave;
    for (; j + 12 < be; j += 16) {
        int2 r0 = perm[j], r1 = perm[j + 4], r2 = perm[j + 8], r3 = perm[j + 12];
        float v0 = bfu(support[(size_t)(r0.x & 0xFFFFF) * DD + lane]);
        float v1 = bfu(support[(size_t)(r1.x & 0xFFFFF) * DD + lane]);
        float v2 = bfu(support[(size_t)(r2.x & 0xFFFFF) * DD + lane]);
        float v3 = bfu(support[(size_t)(r3.x & 0xFFFFF) * DD + lane]);
        atomicAdd(&lagg[((r0.x >> 20) & 31) * DD + lane], __int_as_float(r0.y) * v0);
        atomicAdd(&lagg[((r1.x >> 20) & 31) * DD + lane], __int_as_float(r1.y) * v1);
        atomicAdd(&lagg[((r2.x >> 20) & 31) * DD + lane], __int_as_float(r2.y) * v2);
        atomicAdd(&lagg[((r3.x >> 20) & 31) * DD + lane], __int_as_float(r3.y) * v3);
    }
    for (; j < be; j += 4) {
        int2 r = perm[j];
        float v = bfu(support[(size_t)(r.x & 0xFFFFF) * DD + lane]);
        atomicAdd(&lagg[((r.x >> 20) & 31) * DD + lane], __int_as_float(r.y) * v);
    }
    __syncthreads();

    const int node0 = blockIdx.x * 32;        // always fully in range: 3125*32 == NN
    for (int r = wave; r < 32; r += 4)
        out[(size_t)(node0 + r) * DD + lane] = lagg[r * DD + lane];

    float s = 0.f, sq = 0.f;
#pragma unroll
    for (int r = wave * 8; r < wave * 8 + 8; ++r) {
        float v = lagg[r * DD + lane];
        s += v; sq = fmaf(v, v, sq);
    }
    __syncthreads();
    float* red = lagg;                        // overlay 512 floats
    red[wave * DD + lane] = s;
    red[256 + wave * DD + lane] = sq;
    __syncthreads();
    if (t < DD) {
        float ts = 0.f, tq = 0.f;
#pragma unroll
        for (int g = 0; g < 4; ++g) { ts += red[g * DD + t]; tq += red[256 + g * DD + t]; }
        atomicAdd(&stats[t], ts);
        atomicAdd(&stats[DD + t], tq);
    }
}

// ---------------- K6: fold stats into scale/shift ----------------
__global__ void k_finstats(const float* __restrict__ sums, float* __restrict__ ss,
                           const float* __restrict__ gamma,
                           const float* __restrict__ beta) {
    const int c = threadIdx.x;
    const float invn = 1.0f / NN;
    float mean = sums[c] * invn;
    float var = fmaxf(sums[DD + c] * invn - mean * mean, 0.f);
    float sc = rsqrtf(var + 1e-5f) * gamma[c];
    ss[c] = sc;
    ss[DD + c] = beta[c] - mean * sc;
}

// ---------------- K7: out = relu(out*scale + shift) in-place ----------------
__global__ __launch_bounds__(256) void k_final(float* __restrict__ out,
                                               const float* __restrict__ ss) {
    const size_t idx = ((size_t)blockIdx.x * 256 + threadIdx.x) * 4;
    const int c = (int)(idx & 63);
    float4 v = *(const float4*)(out + idx);
    float4 o;
    o.x = fmaxf(fmaf(v.x, ss[c + 0], ss[DD + c + 0]), 0.f);
    o.y = fmaxf(fmaf(v.y, ss[c + 1], ss[DD + c + 1]), 0.f);
    o.z = fmaxf(fmaf(v.z, ss[c + 2], ss[DD + c + 2]), 0.f);
    o.w = fmaxf(fmaf(v.w, ss[c + 3], ss[DD + c + 3]), 0.f);
    *(float4*)(out + idx) = o;
}

extern "C" void kernel_launch(void* const* d_in, const int* in_sizes, int n_in,
                              void* d_out, int out_size, void* d_ws, size_t ws_size,
                              hipStream_t stream) {
    const float* x     = (const float*)d_in[0];
    const int*   esrc  = (const int*)d_in[1];
    const int*   edst  = (const int*)d_in[2];
    const float* ew    = (const float*)d_in[3];
    const float* W     = (const float*)d_in[4];
    // d_in[5] = bias: cancels exactly in batchnorm (shift-invariant) — unused.
    const float* gamma = (const float*)d_in[6];
    const float* beta  = (const float*)d_in[7];
    float*       out   = (float*)d_out;   // doubles as the agg buffer

    char* ws = (char*)d_ws;
    unsigned short* support = (unsigned short*)ws; ws += (size_t)NN * DD * 2;  // 12.8 MB bf16
    int2*  permA  = (int2*)ws;   ws += (size_t)NE * 8;        // 12.8 MB coarse-grouped
    int2*  perm   = (int2*)ws;   ws += (size_t)NE * 8;        // 12.8 MB fine-grouped
    int*   cnt98  = (int*)ws;    ws += NCOARSE * 4;
    float* stats  = (float*)ws;  ws += 256 * 4;               // sum|sumsq|scale|shift
    int*   cstart = (int*)ws;    ws += (NCOARSE + 1) * 4;
    int*   ctail  = (int*)ws;    ws += NCOARSE * 4;
    int*   bstart = (int*)ws;    ws += (NFINE + 1) * 4;

    // zero cnt98 + stats (adjacent)
    hipMemsetAsync(cnt98, 0, NCOARSE * 4 + 256 * 4, stream);

    k_gemm_hist<<<GEMM_BLOCKS + HIST_BLOCKS, 256, 0, stream>>>(x, W, support, edst, cnt98);
    k_scan98   <<<1, 128, 0, stream>>>(cnt98, cstart, ctail, bstart);
    k_placeA   <<<PLACE_BLOCKS, 256, 0, stream>>>(esrc, edst, ew, ctail, permA);
    k_placeB   <<<NCOARSE, 512, 0, stream>>>(cstart, permA, perm, bstart);
    k_gather   <<<NFINE, 256, 0, stream>>>(bstart, perm, support, out, stats);
    k_finstats <<<1, 64, 0, stream>>>(stats, stats + 2 * DD, gamma, beta);
    k_final    <<<NN * DD / 4 / 256, 256, 0, stream>>>(out, stats + 2 * DD);
}

// Round 7
// 773.288 us; speedup vs baseline: 1.1630x; 1.0205x over previous
//
#include <hip/hip_runtime.h>
#include <hip/hip_bf16.h>

#define NN 100000
#define NE 1600000
#define DD 64
#define NCOARSE 98          // 1024-node coarse buckets (node>>10)
#define NFINE 3125          // 32-node fine buckets (node>>5); 3125*32 == 100000 exactly
#define GEMM_BLOCKS 6250    // NN/16
#define HIST_BLOCKS 125     // NE/12800
#define PLACE_EPB 8192
#define PLACE_BLOCKS 196    // ceil(NE/8192)

__device__ inline float bfu(unsigned short u) { return __uint_as_float((unsigned)u << 16); }
__device__ inline unsigned short f2bf(float f) {
    __hip_bfloat16 h = __float2bfloat16(f);
    unsigned short s; __builtin_memcpy(&s, &h, 2); return s;
}

// ---------------- K1: fused  support_bf16 = x@W  +  coarse dst histogram ----------------
__global__ __launch_bounds__(256) void k_gemm_hist(const float* __restrict__ x,
                                                   const float* __restrict__ Wg,
                                                   unsigned short* __restrict__ support,
                                                   const int* __restrict__ edst,
                                                   int* __restrict__ cnt98) {
    if (blockIdx.x >= GEMM_BLOCKS) {
        __shared__ int h[NCOARSE];
        for (int i = threadIdx.x; i < NCOARSE; i += 256) h[i] = 0;
        __syncthreads();
        const int base = (blockIdx.x - GEMM_BLOCKS) * 12800;
#pragma unroll 5
        for (int k = 0; k < 50; ++k)
            atomicAdd(&h[edst[base + k * 256 + threadIdx.x] >> 10], 1);
        __syncthreads();
        for (int i = threadIdx.x; i < NCOARSE; i += 256)
            if (h[i]) atomicAdd(&cnt98[i], h[i]);
        return;
    }
    __shared__ float Ws[DD * DD];
    for (int i = threadIdx.x; i < DD * DD; i += 256)
        Ws[i] = Wg[i];
    __syncthreads();

    const int wave = threadIdx.x >> 6, lane = threadIdx.x & 63;
    const size_t row0 = (size_t)blockIdx.x * 16 + (size_t)wave * 4;
    const float* xr = x + row0 * DD;

    float acc0 = 0.f, acc1 = 0.f, acc2 = 0.f, acc3 = 0.f;
#pragma unroll
    for (int k = 0; k < DD; k += 4) {
        float4 p0 = *(const float4*)(xr + 0 * DD + k);
        float4 p1 = *(const float4*)(xr + 1 * DD + k);
        float4 p2 = *(const float4*)(xr + 2 * DD + k);
        float4 p3 = *(const float4*)(xr + 3 * DD + k);
        float w0 = Ws[(k + 0) * DD + lane];
        float w1 = Ws[(k + 1) * DD + lane];
        float w2 = Ws[(k + 2) * DD + lane];
        float w3 = Ws[(k + 3) * DD + lane];
        acc0 = fmaf(p0.x, w0, acc0); acc0 = fmaf(p0.y, w1, acc0);
        acc0 = fmaf(p0.z, w2, acc0); acc0 = fmaf(p0.w, w3, acc0);
        acc1 = fmaf(p1.x, w0, acc1); acc1 = fmaf(p1.y, w1, acc1);
        acc1 = fmaf(p1.z, w2, acc1); acc1 = fmaf(p1.w, w3, acc1);
        acc2 = fmaf(p2.x, w0, acc2); acc2 = fmaf(p2.y, w1, acc2);
        acc2 = fmaf(p2.z, w2, acc2); acc2 = fmaf(p2.w, w3, acc2);
        acc3 = fmaf(p3.x, w0, acc3); acc3 = fmaf(p3.y, w1, acc3);
        acc3 = fmaf(p3.z, w2, acc3); acc3 = fmaf(p3.w, w3, acc3);
    }
    unsigned short* sp = support + row0 * DD + lane;
    sp[0 * DD] = f2bf(acc0); sp[1 * DD] = f2bf(acc1);
    sp[2 * DD] = f2bf(acc2); sp[3 * DD] = f2bf(acc3);
}

// ---------------- K2: exclusive scan of 98 coarse counts ----------------
__global__ __launch_bounds__(128) void k_scan98(const int* __restrict__ cnt98,
                                                int* __restrict__ cstart,
                                                int* __restrict__ ctail,
                                                int* __restrict__ bstart) {
    __shared__ int sc[128];
    const int t = threadIdx.x;
    const int v = (t < NCOARSE) ? cnt98[t] : 0;
    sc[t] = v; __syncthreads();
    for (int o = 1; o < 128; o <<= 1) {
        int u = (t >= o) ? sc[t - o] : 0;
        __syncthreads();
        sc[t] += u;
        __syncthreads();
    }
    if (t < NCOARSE) { cstart[t] = sc[t] - v; ctail[t] = sc[t] - v; }
    if (t == 0) { cstart[NCOARSE] = NE; bstart[NFINE] = NE; }
}

// ---------------- K3: placeA — group edges by coarse bucket ----------------
// permA.x = src | (dlocal<<20)  where dlocal = d & 1023 (10 bits);  permA.y = weight bits
__global__ __launch_bounds__(256) void k_placeA(const int* __restrict__ esrc,
                                                const int* __restrict__ edst,
                                                const float* __restrict__ ew,
                                                int* __restrict__ ctail,
                                                int2* __restrict__ permA) {
    __shared__ int lcnt[NCOARSE], loff[NCOARSE];
    for (int i = threadIdx.x; i < NCOARSE; i += 256) lcnt[i] = 0;
    __syncthreads();
    const int e0 = blockIdx.x * PLACE_EPB;
#pragma unroll 4
    for (int k = 0; k < 32; ++k) {
        int e = e0 + k * 256 + threadIdx.x;
        if (e < NE) atomicAdd(&lcnt[edst[e] >> 10], 1);
    }
    __syncthreads();
    for (int i = threadIdx.x; i < NCOARSE; i += 256) {
        int c = lcnt[i];
        loff[i] = c ? atomicAdd(&ctail[i], c) : 0;
    }
    __syncthreads();
#pragma unroll 4
    for (int k = 0; k < 32; ++k) {
        int e = e0 + k * 256 + threadIdx.x;
        if (e < NE) {
            int d = edst[e];
            int p = atomicAdd(&loff[d >> 10], 1);
            permA[p] = make_int2(esrc[e] | ((d & 1023) << 20), __float_as_int(ew[e]));
        }
    }
}

// ---------------- K4: placeB — one block per coarse bucket; distribute into 32 fine buckets ----------------
__global__ __launch_bounds__(512) void k_placeB(const int* __restrict__ cstart,
                                                const int2* __restrict__ permA,
                                                int2* __restrict__ perm,
                                                int* __restrict__ bstart) {
    __shared__ int lcnt[32], lstart[32], loff[32];
    const int c = blockIdx.x, t = threadIdx.x;
    const int cs = cstart[c], ce = cstart[c + 1];
    if (t < 32) lcnt[t] = 0;
    __syncthreads();
    for (int j = cs + t; j < ce; j += 512)
        atomicAdd(&lcnt[(permA[j].x >> 25) & 31], 1);
    __syncthreads();
    if (t == 0) {
        int run = cs;
        for (int k = 0; k < 32; ++k) { lstart[k] = run; loff[k] = run; run += lcnt[k]; }
    }
    __syncthreads();
    if (t < 32) {
        int f = c * 32 + t;
        if (f < NFINE) bstart[f] = lstart[t];
    }
    for (int j = cs + t; j < ce; j += 512) {
        int2 m = permA[j];
        int fl = (m.x >> 25) & 31;
        int p = atomicAdd(&loff[fl], 1);
        perm[p] = make_int2((m.x & 0xFFFFF) | (((m.x >> 20) & 31) << 20), m.y);
    }
}

// ---------------- K5: gather — 1024 thr (16 waves) per 32-node bucket, 8-edge ILP, fused stats ----------------
__global__ __launch_bounds__(1024) void k_gather(const int* __restrict__ bstart,
                                                 const int2* __restrict__ perm,
                                                 const unsigned short* __restrict__ support,
                                                 float* __restrict__ out,
                                                 float* __restrict__ stats) {
    __shared__ float lagg[32 * DD];   // 8 KB = 2048 floats
    const int t = threadIdx.x, wave = t >> 6, lane = t & 63;
    *(float2*)&lagg[t * 2] = make_float2(0.f, 0.f);
    __syncthreads();

    const int bs = bstart[blockIdx.x], be = bstart[blockIdx.x + 1];
    // wave w handles 8-edge groups: [bs + w*8 + 128k, ...+8)
    for (int j = bs + wave * 8; j < be; j += 128) {
        if (j + 7 < be) {
            int2 m0 = perm[j],     m1 = perm[j + 1], m2 = perm[j + 2], m3 = perm[j + 3];
            int2 m4 = perm[j + 4], m5 = perm[j + 5], m6 = perm[j + 6], m7 = perm[j + 7];
            float v0 = bfu(support[(size_t)(m0.x & 0xFFFFF) * DD + lane]);
            float v1 = bfu(support[(size_t)(m1.x & 0xFFFFF) * DD + lane]);
            float v2 = bfu(support[(size_t)(m2.x & 0xFFFFF) * DD + lane]);
            float v3 = bfu(support[(size_t)(m3.x & 0xFFFFF) * DD + lane]);
            float v4 = bfu(support[(size_t)(m4.x & 0xFFFFF) * DD + lane]);
            float v5 = bfu(support[(size_t)(m5.x & 0xFFFFF) * DD + lane]);
            float v6 = bfu(support[(size_t)(m6.x & 0xFFFFF) * DD + lane]);
            float v7 = bfu(support[(size_t)(m7.x & 0xFFFFF) * DD + lane]);
            atomicAdd(&lagg[((m0.x >> 20) & 31) * DD + lane], __int_as_float(m0.y) * v0);
            atomicAdd(&lagg[((m1.x >> 20) & 31) * DD + lane], __int_as_float(m1.y) * v1);
            atomicAdd(&lagg[((m2.x >> 20) & 31) * DD + lane], __int_as_float(m2.y) * v2);
            atomicAdd(&lagg[((m3.x >> 20) & 31) * DD + lane], __int_as_float(m3.y) * v3);
            atomicAdd(&lagg[((m4.x >> 20) & 31) * DD + lane], __int_as_float(m4.y) * v4);
            atomicAdd(&lagg[((m5.x >> 20) & 31) * DD + lane], __int_as_float(m5.y) * v5);
            atomicAdd(&lagg[((m6.x >> 20) & 31) * DD + lane], __int_as_float(m6.y) * v6);
            atomicAdd(&lagg[((m7.x >> 20) & 31) * DD + lane], __int_as_float(m7.y) * v7);
        } else {
            for (int jj = j; jj < be; ++jj) {
                int2 m = perm[jj];
                float v = bfu(support[(size_t)(m.x & 0xFFFFF) * DD + lane]);
                atomicAdd(&lagg[((m.x >> 20) & 31) * DD + lane], __int_as_float(m.y) * v);
            }
        }
    }
    __syncthreads();

    const int node0 = blockIdx.x * 32;        // 3125*32 == NN exactly
    const int r0 = wave * 2, r1 = wave * 2 + 1;
    float a0 = lagg[r0 * DD + lane], a1 = lagg[r1 * DD + lane];
    out[(size_t)(node0 + r0) * DD + lane] = a0;
    out[(size_t)(node0 + r1) * DD + lane] = a1;

    // fused column stats
    float s = a0 + a1;
    float sq = fmaf(a0, a0, a1 * a1);
    __syncthreads();
    float* red = lagg;                        // overlay: 16*64 s + 16*64 sq = 2048 floats
    red[wave * DD + lane] = s;
    red[1024 + wave * DD + lane] = sq;
    __syncthreads();
    if (t < DD) {
        float ts = 0.f, tq = 0.f;
#pragma unroll
        for (int g = 0; g < 16; ++g) { ts += red[g * DD + t]; tq += red[1024 + g * DD + t]; }
        atomicAdd(&stats[t], ts);
        atomicAdd(&stats[DD + t], tq);
    }
}

// ---------------- K6: fold stats into scale/shift ----------------
__global__ void k_finstats(const float* __restrict__ sums, float* __restrict__ ss,
                           const float* __restrict__ gamma,
                           const float* __restrict__ beta) {
    const int c = threadIdx.x;
    const float invn = 1.0f / NN;
    float mean = sums[c] * invn;
    float var = fmaxf(sums[DD + c] * invn - mean * mean, 0.f);
    float sc = rsqrtf(var + 1e-5f) * gamma[c];
    ss[c] = sc;
    ss[DD + c] = beta[c] - mean * sc;
}

// ---------------- K7: out = relu(out*scale + shift) in-place ----------------
__global__ __launch_bounds__(256) void k_final(float* __restrict__ out,
                                               const float* __restrict__ ss) {
    const size_t idx = ((size_t)blockIdx.x * 256 + threadIdx.x) * 4;
    const int c = (int)(idx & 63);
    float4 v = *(const float4*)(out + idx);
    float4 o;
    o.x = fmaxf(fmaf(v.x, ss[c + 0], ss[DD + c + 0]), 0.f);
    o.y = fmaxf(fmaf(v.y, ss[c + 1], ss[DD + c + 1]), 0.f);
    o.z = fmaxf(fmaf(v.z, ss[c + 2], ss[DD + c + 2]), 0.f);
    o.w = fmaxf(fmaf(v.w, ss[c + 3], ss[DD + c + 3]), 0.f);
    *(float4*)(out + idx) = o;
}

extern "C" void kernel_launch(void* const* d_in, const int* in_sizes, int n_in,
                              void* d_out, int out_size, void* d_ws, size_t ws_size,
                              hipStream_t stream) {
    const float* x     = (const float*)d_in[0];
    const int*   esrc  = (const int*)d_in[1];
    const int*   edst  = (const int*)d_in[2];
    const float* ew    = (const float*)d_in[3];
    const float* W     = (const float*)d_in[4];
    // d_in[5] = bias: cancels exactly in batchnorm (shift-invariant) — unused.
    const float* gamma = (const float*)d_in[6];
    const float* beta  = (const float*)d_in[7];
    float*       out   = (float*)d_out;   // doubles as the agg buffer

    char* ws = (char*)d_ws;
    unsigned short* support = (unsigned short*)ws; ws += (size_t)NN * DD * 2;  // 12.8 MB bf16
    int2*  permA  = (int2*)ws;   ws += (size_t)NE * 8;        // 12.8 MB coarse-grouped
    int2*  perm   = (int2*)ws;   ws += (size_t)NE * 8;        // 12.8 MB fine-grouped
    int*   cnt98  = (int*)ws;    ws += NCOARSE * 4;
    float* stats  = (float*)ws;  ws += 256 * 4;               // sum|sumsq|scale|shift
    int*   cstart = (int*)ws;    ws += (NCOARSE + 1) * 4;
    int*   ctail  = (int*)ws;    ws += NCOARSE * 4;
    int*   bstart = (int*)ws;    ws += (NFINE + 1) * 4;

    // zero cnt98 + stats (adjacent)
    hipMemsetAsync(cnt98, 0, NCOARSE * 4 + 256 * 4, stream);

    k_gemm_hist<<<GEMM_BLOCKS + HIST_BLOCKS, 256, 0, stream>>>(x, W, support, edst, cnt98);
    k_scan98   <<<1, 128, 0, stream>>>(cnt98, cstart, ctail, bstart);
    k_placeA   <<<PLACE_BLOCKS, 256, 0, stream>>>(esrc, edst, ew, ctail, permA);
    k_placeB   <<<NCOARSE, 512, 0, stream>>>(cstart, permA, perm, bstart);
    k_gather   <<<NFINE, 1024, 0, stream>>>(bstart, perm, support, out, stats);
    k_finstats <<<1, 64, 0, stream>>>(stats, stats + 2 * DD, gamma, beta);
    k_final    <<<NN * DD / 4 / 256, 256, 0, stream>>>(out, stats + 2 * DD);
}

// Round 8
// 365.604 us; speedup vs baseline: 2.4599x; 2.1151x over previous
//
#include <hip/hip_runtime.h>
#include <hip/hip_bf16.h>

#define NN 100000
#define NE 1600000
#define DD 64
#define NCOARSE 98          // 1024-node coarse buckets (node>>10)
#define GEMM_BLOCKS 6250    // NN/16
#define HIST_BLOCKS 125     // NE/12800
#define PLACE_EPB 8192
#define PLACE_BLOCKS 196    // ceil(NE/8192)

__device__ inline unsigned short f2bf(float f) {
    __hip_bfloat16 h = __float2bfloat16(f);
    unsigned short s; __builtin_memcpy(&s, &h, 2); return s;
}

// ---------------- K1: fused  support_bf16 = x@W  +  coarse dst histogram ----------------
__global__ __launch_bounds__(256) void k_gemm_hist(const float* __restrict__ x,
                                                   const float* __restrict__ Wg,
                                                   unsigned short* __restrict__ support,
                                                   const int* __restrict__ edst,
                                                   int* __restrict__ cnt98) {
    if (blockIdx.x >= GEMM_BLOCKS) {
        __shared__ int h[NCOARSE];
        for (int i = threadIdx.x; i < NCOARSE; i += 256) h[i] = 0;
        __syncthreads();
        const int base = (blockIdx.x - GEMM_BLOCKS) * 12800;
#pragma unroll 5
        for (int k = 0; k < 50; ++k)
            atomicAdd(&h[edst[base + k * 256 + threadIdx.x] >> 10], 1);
        __syncthreads();
        for (int i = threadIdx.x; i < NCOARSE; i += 256)
            if (h[i]) atomicAdd(&cnt98[i], h[i]);
        return;
    }
    __shared__ float Ws[DD * DD];
    for (int i = threadIdx.x; i < DD * DD; i += 256)
        Ws[i] = Wg[i];
    __syncthreads();

    const int wave = threadIdx.x >> 6, lane = threadIdx.x & 63;
    const size_t row0 = (size_t)blockIdx.x * 16 + (size_t)wave * 4;
    const float* xr = x + row0 * DD;

    float acc0 = 0.f, acc1 = 0.f, acc2 = 0.f, acc3 = 0.f;
#pragma unroll
    for (int k = 0; k < DD; k += 4) {
        float4 p0 = *(const float4*)(xr + 0 * DD + k);
        float4 p1 = *(const float4*)(xr + 1 * DD + k);
        float4 p2 = *(const float4*)(xr + 2 * DD + k);
        float4 p3 = *(const float4*)(xr + 3 * DD + k);
        float w0 = Ws[(k + 0) * DD + lane];
        float w1 = Ws[(k + 1) * DD + lane];
        float w2 = Ws[(k + 2) * DD + lane];
        float w3 = Ws[(k + 3) * DD + lane];
        acc0 = fmaf(p0.x, w0, acc0); acc0 = fmaf(p0.y, w1, acc0);
        acc0 = fmaf(p0.z, w2, acc0); acc0 = fmaf(p0.w, w3, acc0);
        acc1 = fmaf(p1.x, w0, acc1); acc1 = fmaf(p1.y, w1, acc1);
        acc1 = fmaf(p1.z, w2, acc1); acc1 = fmaf(p1.w, w3, acc1);
        acc2 = fmaf(p2.x, w0, acc2); acc2 = fmaf(p2.y, w1, acc2);
        acc2 = fmaf(p2.z, w2, acc2); acc2 = fmaf(p2.w, w3, acc2);
        acc3 = fmaf(p3.x, w0, acc3); acc3 = fmaf(p3.y, w1, acc3);
        acc3 = fmaf(p3.z, w2, acc3); acc3 = fmaf(p3.w, w3, acc3);
    }
    unsigned short* sp = support + row0 * DD + lane;
    sp[0 * DD] = f2bf(acc0); sp[1 * DD] = f2bf(acc1);
    sp[2 * DD] = f2bf(acc2); sp[3 * DD] = f2bf(acc3);
}

// ---------------- K2: exclusive scan of 98 coarse counts ----------------
__global__ __launch_bounds__(128) void k_scan98(const int* __restrict__ cnt98,
                                                int* __restrict__ cstart,
                                                int* __restrict__ ctail,
                                                int* __restrict__ bstart) {
    __shared__ int sc[128];
    const int t = threadIdx.x;
    const int v = (t < NCOARSE) ? cnt98[t] : 0;
    sc[t] = v; __syncthreads();
    for (int o = 1; o < 128; o <<= 1) {
        int u = (t >= o) ? sc[t - o] : 0;
        __syncthreads();
        sc[t] += u;
        __syncthreads();
    }
    if (t < NCOARSE) { cstart[t] = sc[t] - v; ctail[t] = sc[t] - v; }
    if (t == 0) { cstart[NCOARSE] = NE; bstart[NN] = NE; }
}

// ---------------- K3: placeA — group edges by coarse bucket (coalesced chunk writes) ----------------
// permA.x = src | (dlocal<<20)  (src<2^17, dlocal 10 bits);  permA.y = weight bits
__global__ __launch_bounds__(256) void k_placeA(const int* __restrict__ esrc,
                                                const int* __restrict__ edst,
                                                const float* __restrict__ ew,
                                                int* __restrict__ ctail,
                                                int2* __restrict__ permA) {
    __shared__ int lcnt[NCOARSE], loff[NCOARSE];
    for (int i = threadIdx.x; i < NCOARSE; i += 256) lcnt[i] = 0;
    __syncthreads();
    const int e0 = blockIdx.x * PLACE_EPB;
#pragma unroll 4
    for (int k = 0; k < 32; ++k) {
        int e = e0 + k * 256 + threadIdx.x;
        if (e < NE) atomicAdd(&lcnt[edst[e] >> 10], 1);
    }
    __syncthreads();
    for (int i = threadIdx.x; i < NCOARSE; i += 256) {
        int c = lcnt[i];
        loff[i] = c ? atomicAdd(&ctail[i], c) : 0;
    }
    __syncthreads();
#pragma unroll 4
    for (int k = 0; k < 32; ++k) {
        int e = e0 + k * 256 + threadIdx.x;
        if (e < NE) {
            int d = edst[e];
            int p = atomicAdd(&loff[d >> 10], 1);
            permA[p] = make_int2(esrc[e] | ((d & 1023) << 20), __float_as_int(ew[e]));
        }
    }
}

// ---------------- K4: placeB — exact per-node CSR within each coarse bucket ----------------
// one block per coarse bucket; 1024-node LDS hist + scan; writes bstart[node] and perm[] (pure src)
__global__ __launch_bounds__(1024) void k_placeB(const int* __restrict__ cstart,
                                                 const int2* __restrict__ permA,
                                                 int2* __restrict__ perm,
                                                 int* __restrict__ bstart) {
    __shared__ int sc[1024], loff[1024];
    const int c = blockIdx.x, t = threadIdx.x;
    const int cs = cstart[c], ce = cstart[c + 1];
    sc[t] = 0;
    __syncthreads();
    for (int j = cs + t; j < ce; j += 1024)
        atomicAdd(&sc[(permA[j].x >> 20) & 1023], 1);
    __syncthreads();
    const int cnt = sc[t];
    for (int o = 1; o < 1024; o <<= 1) {
        int u = (t >= o) ? sc[t - o] : 0;
        __syncthreads();
        sc[t] += u;
        __syncthreads();
    }
    const int base = cs + sc[t] - cnt;
    loff[t] = base;
    const int node = c * 1024 + t;
    if (node < NN) bstart[node] = base;
    __syncthreads();
    for (int j = cs + t; j < ce; j += 1024) {
        int2 m = permA[j];
        int p = atomicAdd(&loff[(m.x >> 20) & 1023], 1);
        perm[p] = make_int2(m.x & 0xFFFFF, m.y);
    }
}

// ---------------- K5: gather — one wave per node, register accumulate, dword bf16 loads ----------------
// half-wave = one edge: lane hl in [0,32) covers columns (2hl, 2hl+1) via one uint load
__global__ __launch_bounds__(256) void k_gather(const int* __restrict__ bstart,
                                                const int2* __restrict__ perm,
                                                const unsigned* __restrict__ support2,
                                                float* __restrict__ out) {
    const int wave = threadIdx.x >> 6, lane = threadIdx.x & 63;
    const int half = lane >> 5, hl = lane & 31;
    const int d = blockIdx.x * 4 + wave;            // grid = NN/4 exactly
    const int bs = bstart[d], be = bstart[d + 1];
    float ax = 0.f, ay = 0.f, bx = 0.f, by = 0.f;
    int j0 = bs;
    for (; j0 + 3 < be; j0 += 4) {
        int2 mA = perm[j0 + half];
        int2 mB = perm[j0 + 2 + half];
        unsigned pA = support2[(size_t)mA.x * 32 + hl];
        unsigned pB = support2[(size_t)mB.x * 32 + hl];
        float wA = __int_as_float(mA.y), wB = __int_as_float(mB.y);
        ax = fmaf(wA, __uint_as_float(pA << 16), ax);
        ay = fmaf(wA, __uint_as_float(pA & 0xffff0000u), ay);
        bx = fmaf(wB, __uint_as_float(pB << 16), bx);
        by = fmaf(wB, __uint_as_float(pB & 0xffff0000u), by);
    }
    for (; j0 + half < be; j0 += 2) {
        int2 m = perm[j0 + half];
        unsigned p = support2[(size_t)m.x * 32 + hl];
        float w = __int_as_float(m.y);
        ax = fmaf(w, __uint_as_float(p << 16), ax);
        ay = fmaf(w, __uint_as_float(p & 0xffff0000u), ay);
    }
    ax += bx; ay += by;
    ax += __shfl_xor(ax, 32);
    ay += __shfl_xor(ay, 32);
    if (half == 0)
        *(float2*)(out + (size_t)d * DD + 2 * hl) = make_float2(ax, ay);
}

// ---------------- K6: per-column sum & sumsq ----------------
__device__ inline float4 shfl_down4(float4 v, int dd) {
    v.x = __shfl_down(v.x, dd, 64); v.y = __shfl_down(v.y, dd, 64);
    v.z = __shfl_down(v.z, dd, 64); v.w = __shfl_down(v.w, dd, 64);
    return v;
}
__device__ inline float4 add4(float4 a, float4 b) {
    a.x += b.x; a.y += b.y; a.z += b.z; a.w += b.w; return a;
}

__global__ __launch_bounds__(256) void k_stats(const float* __restrict__ agg,
                                               float* __restrict__ stats) {
    const int lane = threadIdx.x & 63, wave = threadIdx.x >> 6;
    const int q = lane & 15, sub = lane >> 4;
    float4 s = {0, 0, 0, 0}, sq = {0, 0, 0, 0};
    const int stride = gridDim.x * 16;
    for (int row = (blockIdx.x * 4 + wave) * 4 + sub; row < NN; row += stride) {
        float4 v = *(const float4*)(agg + (size_t)row * DD + q * 4);
        s.x += v.x; s.y += v.y; s.z += v.z; s.w += v.w;
        sq.x = fmaf(v.x, v.x, sq.x); sq.y = fmaf(v.y, v.y, sq.y);
        sq.z = fmaf(v.z, v.z, sq.z); sq.w = fmaf(v.w, v.w, sq.w);
    }
    s = add4(s, shfl_down4(s, 32));  s = add4(s, shfl_down4(s, 16));
    sq = add4(sq, shfl_down4(sq, 32)); sq = add4(sq, shfl_down4(sq, 16));

    __shared__ float red[2][4][DD];
    if (lane < 16) {
        red[0][wave][q * 4 + 0] = s.x;  red[0][wave][q * 4 + 1] = s.y;
        red[0][wave][q * 4 + 2] = s.z;  red[0][wave][q * 4 + 3] = s.w;
        red[1][wave][q * 4 + 0] = sq.x; red[1][wave][q * 4 + 1] = sq.y;
        red[1][wave][q * 4 + 2] = sq.z; red[1][wave][q * 4 + 3] = sq.w;
    }
    __syncthreads();
    if (threadIdx.x < DD) {
        const int c = threadIdx.x;
        atomicAdd(&stats[c],      red[0][0][c] + red[0][1][c] + red[0][2][c] + red[0][3][c]);
        atomicAdd(&stats[DD + c], red[1][0][c] + red[1][1][c] + red[1][2][c] + red[1][3][c]);
    }
}

// ---------------- K7: fold stats into scale/shift ----------------
__global__ void k_finstats(const float* __restrict__ sums, float* __restrict__ ss,
                           const float* __restrict__ gamma,
                           const float* __restrict__ beta) {
    const int c = threadIdx.x;
    const float invn = 1.0f / NN;
    float mean = sums[c] * invn;
    float var = fmaxf(sums[DD + c] * invn - mean * mean, 0.f);
    float sc = rsqrtf(var + 1e-5f) * gamma[c];
    ss[c] = sc;
    ss[DD + c] = beta[c] - mean * sc;
}

// ---------------- K8: out = relu(out*scale + shift) in-place ----------------
__global__ __launch_bounds__(256) void k_final(float* __restrict__ out,
                                               const float* __restrict__ ss) {
    const size_t idx = ((size_t)blockIdx.x * 256 + threadIdx.x) * 4;
    const int c = (int)(idx & 63);
    float4 v = *(const float4*)(out + idx);
    float4 o;
    o.x = fmaxf(fmaf(v.x, ss[c + 0], ss[DD + c + 0]), 0.f);
    o.y = fmaxf(fmaf(v.y, ss[c + 1], ss[DD + c + 1]), 0.f);
    o.z = fmaxf(fmaf(v.z, ss[c + 2], ss[DD + c + 2]), 0.f);
    o.w = fmaxf(fmaf(v.w, ss[c + 3], ss[DD + c + 3]), 0.f);
    *(float4*)(out + idx) = o;
}

extern "C" void kernel_launch(void* const* d_in, const int* in_sizes, int n_in,
                              void* d_out, int out_size, void* d_ws, size_t ws_size,
                              hipStream_t stream) {
    const float* x     = (const float*)d_in[0];
    const int*   esrc  = (const int*)d_in[1];
    const int*   edst  = (const int*)d_in[2];
    const float* ew    = (const float*)d_in[3];
    const float* W     = (const float*)d_in[4];
    // d_in[5] = bias: cancels exactly in batchnorm (shift-invariant) — unused.
    const float* gamma = (const float*)d_in[6];
    const float* beta  = (const float*)d_in[7];
    float*       out   = (float*)d_out;   // doubles as the agg buffer

    char* ws = (char*)d_ws;
    unsigned short* support = (unsigned short*)ws; ws += (size_t)NN * DD * 2;  // 12.8 MB bf16
    int2*  permA  = (int2*)ws;   ws += (size_t)NE * 8;        // 12.8 MB coarse-grouped
    int2*  perm   = (int2*)ws;   ws += (size_t)NE * 8;        // 12.8 MB per-node CSR
    int*   cnt98  = (int*)ws;    ws += NCOARSE * 4;
    float* stats  = (float*)ws;  ws += 256 * 4;               // sum|sumsq|scale|shift
    int*   cstart = (int*)ws;    ws += (NCOARSE + 1) * 4;
    int*   ctail  = (int*)ws;    ws += NCOARSE * 4;
    int*   bstart = (int*)ws;    ws += (NN + 4) * 4;          // per-node CSR offsets

    // zero cnt98 + stats (adjacent)
    hipMemsetAsync(cnt98, 0, NCOARSE * 4 + 256 * 4, stream);

    k_gemm_hist<<<GEMM_BLOCKS + HIST_BLOCKS, 256, 0, stream>>>(x, W, support, edst, cnt98);
    k_scan98   <<<1, 128, 0, stream>>>(cnt98, cstart, ctail, bstart);
    k_placeA   <<<PLACE_BLOCKS, 256, 0, stream>>>(esrc, edst, ew, ctail, permA);
    k_placeB   <<<NCOARSE, 1024, 0, stream>>>(cstart, permA, perm, bstart);
    k_gather   <<<NN / 4, 256, 0, stream>>>(bstart, perm, (const unsigned*)support, out);
    k_stats    <<<2048, 256, 0, stream>>>(out, stats);
    k_finstats <<<1, 64, 0, stream>>>(stats, stats + 2 * DD, gamma, beta);
    k_final    <<<NN * DD / 4 / 256, 256, 0, stream>>>(out, stats + 2 * DD);
}

// Round 9
// 305.212 us; speedup vs baseline: 2.9467x; 1.1979x over previous
//
#include <hip/hip_runtime.h>
#include <hip/hip_bf16.h>

#define NN 100000
#define NE 1600000
#define DD 64
#define NCOARSE 98          // 1024-node coarse buckets (node>>10)
#define NTILE 6250          // NN/16 row-tiles
#define GEMM_GS 1024        // persistent gemm blocks (grid-stride)
#define HIST_BLOCKS 125     // NE/12800
#define PLACE_EPB 8192
#define PLACE_BLOCKS 196    // ceil(NE/8192)
#define STAT_BLOCKS 256

__device__ inline unsigned short f2bf(float f) {
    __hip_bfloat16 h = __float2bfloat16(f);
    unsigned short s; __builtin_memcpy(&s, &h, 2); return s;
}

// ---------------- K1: fused  support_bf16 = x@W (grid-stride)  +  coarse dst histogram ----------------
__global__ __launch_bounds__(256) void k_gemm_hist(const float* __restrict__ x,
                                                   const float* __restrict__ Wg,
                                                   unsigned short* __restrict__ support,
                                                   const int* __restrict__ edst,
                                                   int* __restrict__ cnt98) {
    if (blockIdx.x >= GEMM_GS) {
        __shared__ int h[NCOARSE];
        for (int i = threadIdx.x; i < NCOARSE; i += 256) h[i] = 0;
        __syncthreads();
        const int base = (blockIdx.x - GEMM_GS) * 12800;
#pragma unroll 5
        for (int k = 0; k < 50; ++k)
            atomicAdd(&h[edst[base + k * 256 + threadIdx.x] >> 10], 1);
        __syncthreads();
        for (int i = threadIdx.x; i < NCOARSE; i += 256)
            if (h[i]) atomicAdd(&cnt98[i], h[i]);
        return;
    }
    __shared__ float Ws[DD * DD];
    for (int i = threadIdx.x; i < DD * DD; i += 256)
        Ws[i] = Wg[i];
    __syncthreads();

    const int wave = threadIdx.x >> 6, lane = threadIdx.x & 63;
    for (int tile = blockIdx.x; tile < NTILE; tile += GEMM_GS) {
        const size_t row0 = (size_t)tile * 16 + (size_t)wave * 4;
        const float* xr = x + row0 * DD;
        float acc0 = 0.f, acc1 = 0.f, acc2 = 0.f, acc3 = 0.f;
#pragma unroll
        for (int k = 0; k < DD; k += 4) {
            float4 p0 = *(const float4*)(xr + 0 * DD + k);
            float4 p1 = *(const float4*)(xr + 1 * DD + k);
            float4 p2 = *(const float4*)(xr + 2 * DD + k);
            float4 p3 = *(const float4*)(xr + 3 * DD + k);
            float w0 = Ws[(k + 0) * DD + lane];
            float w1 = Ws[(k + 1) * DD + lane];
            float w2 = Ws[(k + 2) * DD + lane];
            float w3 = Ws[(k + 3) * DD + lane];
            acc0 = fmaf(p0.x, w0, acc0); acc0 = fmaf(p0.y, w1, acc0);
            acc0 = fmaf(p0.z, w2, acc0); acc0 = fmaf(p0.w, w3, acc0);
            acc1 = fmaf(p1.x, w0, acc1); acc1 = fmaf(p1.y, w1, acc1);
            acc1 = fmaf(p1.z, w2, acc1); acc1 = fmaf(p1.w, w3, acc1);
            acc2 = fmaf(p2.x, w0, acc2); acc2 = fmaf(p2.y, w1, acc2);
            acc2 = fmaf(p2.z, w2, acc2); acc2 = fmaf(p2.w, w3, acc2);
            acc3 = fmaf(p3.x, w0, acc3); acc3 = fmaf(p3.y, w1, acc3);
            acc3 = fmaf(p3.z, w2, acc3); acc3 = fmaf(p3.w, w3, acc3);
        }
        unsigned short* sp = support + row0 * DD + lane;
        sp[0 * DD] = f2bf(acc0); sp[1 * DD] = f2bf(acc1);
        sp[2 * DD] = f2bf(acc2); sp[3 * DD] = f2bf(acc3);
    }
}

// ---------------- K2: exclusive scan of 98 coarse counts ----------------
__global__ __launch_bounds__(128) void k_scan98(const int* __restrict__ cnt98,
                                                int* __restrict__ cstart,
                                                int* __restrict__ ctail,
                                                int* __restrict__ bstart) {
    __shared__ int sc[128];
    const int t = threadIdx.x;
    const int v = (t < NCOARSE) ? cnt98[t] : 0;
    sc[t] = v; __syncthreads();
    for (int o = 1; o < 128; o <<= 1) {
        int u = (t >= o) ? sc[t - o] : 0;
        __syncthreads();
        sc[t] += u;
        __syncthreads();
    }
    if (t < NCOARSE) { cstart[t] = sc[t] - v; ctail[t] = sc[t] - v; }
    if (t == 0) { cstart[NCOARSE] = NE; bstart[NN] = NE; }
}

// ---------------- K3: placeA — group edges by coarse bucket ----------------
// permA.x = src | (dlocal<<20)  (src<2^17, dlocal 10 bits);  permA.y = weight bits
__global__ __launch_bounds__(256) void k_placeA(const int* __restrict__ esrc,
                                                const int* __restrict__ edst,
                                                const float* __restrict__ ew,
                                                int* __restrict__ ctail,
                                                int2* __restrict__ permA) {
    __shared__ int lcnt[NCOARSE], loff[NCOARSE];
    for (int i = threadIdx.x; i < NCOARSE; i += 256) lcnt[i] = 0;
    __syncthreads();
    const int e0 = blockIdx.x * PLACE_EPB;
#pragma unroll 4
    for (int k = 0; k < 32; ++k) {
        int e = e0 + k * 256 + threadIdx.x;
        if (e < NE) atomicAdd(&lcnt[edst[e] >> 10], 1);
    }
    __syncthreads();
    for (int i = threadIdx.x; i < NCOARSE; i += 256) {
        int c = lcnt[i];
        loff[i] = c ? atomicAdd(&ctail[i], c) : 0;
    }
    __syncthreads();
#pragma unroll 4
    for (int k = 0; k < 32; ++k) {
        int e = e0 + k * 256 + threadIdx.x;
        if (e < NE) {
            int d = edst[e];
            int p = atomicAdd(&loff[d >> 10], 1);
            permA[p] = make_int2(esrc[e] | ((d & 1023) << 20), __float_as_int(ew[e]));
        }
    }
}

// ---------------- K4: placeB — exact per-node CSR within each coarse bucket ----------------
__global__ __launch_bounds__(1024) void k_placeB(const int* __restrict__ cstart,
                                                 const int2* __restrict__ permA,
                                                 int2* __restrict__ perm,
                                                 int* __restrict__ bstart) {
    __shared__ int sc[1024], loff[1024];
    const int c = blockIdx.x, t = threadIdx.x;
    const int cs = cstart[c], ce = cstart[c + 1];
    sc[t] = 0;
    __syncthreads();
    for (int j = cs + t; j < ce; j += 1024)
        atomicAdd(&sc[(permA[j].x >> 20) & 1023], 1);
    __syncthreads();
    const int cnt = sc[t];
    for (int o = 1; o < 1024; o <<= 1) {
        int u = (t >= o) ? sc[t - o] : 0;
        __syncthreads();
        sc[t] += u;
        __syncthreads();
    }
    const int base = cs + sc[t] - cnt;
    loff[t] = base;
    const int node = c * 1024 + t;
    if (node < NN) bstart[node] = base;
    __syncthreads();
    for (int j = cs + t; j < ce; j += 1024) {
        int2 m = permA[j];
        int p = atomicAdd(&loff[(m.x >> 20) & 1023], 1);
        perm[p] = make_int2(m.x & 0xFFFFF, m.y);
    }
}

// ---------------- K5: gather — one wave per node, register accumulate, dword bf16 loads ----------------
__global__ __launch_bounds__(256) void k_gather(const int* __restrict__ bstart,
                                                const int2* __restrict__ perm,
                                                const unsigned* __restrict__ support2,
                                                float* __restrict__ out) {
    const int wave = threadIdx.x >> 6, lane = threadIdx.x & 63;
    const int half = lane >> 5, hl = lane & 31;
    const int d = blockIdx.x * 4 + wave;            // grid = NN/4 exactly
    const int bs = bstart[d], be = bstart[d + 1];
    float ax = 0.f, ay = 0.f, bx = 0.f, by = 0.f;
    int j0 = bs;
    for (; j0 + 3 < be; j0 += 4) {
        int2 mA = perm[j0 + half];
        int2 mB = perm[j0 + 2 + half];
        unsigned pA = support2[(size_t)mA.x * 32 + hl];
        unsigned pB = support2[(size_t)mB.x * 32 + hl];
        float wA = __int_as_float(mA.y), wB = __int_as_float(mB.y);
        ax = fmaf(wA, __uint_as_float(pA << 16), ax);
        ay = fmaf(wA, __uint_as_float(pA & 0xffff0000u), ay);
        bx = fmaf(wB, __uint_as_float(pB << 16), bx);
        by = fmaf(wB, __uint_as_float(pB & 0xffff0000u), by);
    }
    for (; j0 + half < be; j0 += 2) {
        int2 m = perm[j0 + half];
        unsigned p = support2[(size_t)m.x * 32 + hl];
        float w = __int_as_float(m.y);
        ax = fmaf(w, __uint_as_float(p << 16), ax);
        ay = fmaf(w, __uint_as_float(p & 0xffff0000u), ay);
    }
    ax += bx; ay += by;
    ax += __shfl_xor(ax, 32);
    ay += __shfl_xor(ay, 32);
    if (half == 0)
        *(float2*)(out + (size_t)d * DD + 2 * hl) = make_float2(ax, ay);
}

// ---------------- K6: per-column sum & sumsq -> per-block partials (NO atomics) ----------------
__device__ inline float4 shfl_down4(float4 v, int dd) {
    v.x = __shfl_down(v.x, dd, 64); v.y = __shfl_down(v.y, dd, 64);
    v.z = __shfl_down(v.z, dd, 64); v.w = __shfl_down(v.w, dd, 64);
    return v;
}
__device__ inline float4 add4(float4 a, float4 b) {
    a.x += b.x; a.y += b.y; a.z += b.z; a.w += b.w; return a;
}

__global__ __launch_bounds__(256) void k_stats(const float* __restrict__ agg,
                                               float* __restrict__ pstat) {
    const int lane = threadIdx.x & 63, wave = threadIdx.x >> 6;
    const int q = lane & 15, sub = lane >> 4;
    float4 s = {0, 0, 0, 0}, sq = {0, 0, 0, 0};
    const int stride = gridDim.x * 16;
    for (int row = (blockIdx.x * 4 + wave) * 4 + sub; row < NN; row += stride) {
        float4 v = *(const float4*)(agg + (size_t)row * DD + q * 4);
        s.x += v.x; s.y += v.y; s.z += v.z; s.w += v.w;
        sq.x = fmaf(v.x, v.x, sq.x); sq.y = fmaf(v.y, v.y, sq.y);
        sq.z = fmaf(v.z, v.z, sq.z); sq.w = fmaf(v.w, v.w, sq.w);
    }
    s = add4(s, shfl_down4(s, 32));  s = add4(s, shfl_down4(s, 16));
    sq = add4(sq, shfl_down4(sq, 32)); sq = add4(sq, shfl_down4(sq, 16));

    __shared__ float red[2][4][DD];
    if (lane < 16) {
        red[0][wave][q * 4 + 0] = s.x;  red[0][wave][q * 4 + 1] = s.y;
        red[0][wave][q * 4 + 2] = s.z;  red[0][wave][q * 4 + 3] = s.w;
        red[1][wave][q * 4 + 0] = sq.x; red[1][wave][q * 4 + 1] = sq.y;
        red[1][wave][q * 4 + 2] = sq.z; red[1][wave][q * 4 + 3] = sq.w;
    }
    __syncthreads();
    if (threadIdx.x < 2 * DD) {
        const int t = threadIdx.x;           // 0..63 = sum, 64..127 = sumsq
        const int part = t >> 6, c = t & 63;
        pstat[blockIdx.x * 2 * DD + t] =
            red[part][0][c] + red[part][1][c] + red[part][2][c] + red[part][3][c];
    }
}

// ---------------- K7: reduce partials + fold into scale/shift ----------------
__global__ __launch_bounds__(128) void k_finstats(const float* __restrict__ pstat,
                                                  float* __restrict__ ss,
                                                  const float* __restrict__ gamma,
                                                  const float* __restrict__ beta) {
    const int t = threadIdx.x;               // 0..127
    float acc = 0.f;
    for (int b = 0; b < STAT_BLOCKS; ++b)
        acc += pstat[b * 2 * DD + t];
    __shared__ float red[2 * DD];
    red[t] = acc;
    __syncthreads();
    if (t < DD) {
        const float invn = 1.0f / NN;
        float mean = red[t] * invn;
        float var = fmaxf(red[DD + t] * invn - mean * mean, 0.f);
        float sc = rsqrtf(var + 1e-5f) * gamma[t];
        ss[t] = sc;
        ss[DD + t] = beta[t] - mean * sc;
    }
}

// ---------------- K8: out = relu(out*scale + shift) in-place ----------------
__global__ __launch_bounds__(256) void k_final(float* __restrict__ out,
                                               const float* __restrict__ ss) {
    const size_t idx = ((size_t)blockIdx.x * 256 + threadIdx.x) * 4;
    const int c = (int)(idx & 63);
    float4 v = *(const float4*)(out + idx);
    float4 o;
    o.x = fmaxf(fmaf(v.x, ss[c + 0], ss[DD + c + 0]), 0.f);
    o.y = fmaxf(fmaf(v.y, ss[c + 1], ss[DD + c + 1]), 0.f);
    o.z = fmaxf(fmaf(v.z, ss[c + 2], ss[DD + c + 2]), 0.f);
    o.w = fmaxf(fmaf(v.w, ss[c + 3], ss[DD + c + 3]), 0.f);
    *(float4*)(out + idx) = o;
}

extern "C" void kernel_launch(void* const* d_in, const int* in_sizes, int n_in,
                              void* d_out, int out_size, void* d_ws, size_t ws_size,
                              hipStream_t stream) {
    const float* x     = (const float*)d_in[0];
    const int*   esrc  = (const int*)d_in[1];
    const int*   edst  = (const int*)d_in[2];
    const float* ew    = (const float*)d_in[3];
    const float* W     = (const float*)d_in[4];
    // d_in[5] = bias: cancels exactly in batchnorm (shift-invariant) — unused.
    const float* gamma = (const float*)d_in[6];
    const float* beta  = (const float*)d_in[7];
    float*       out   = (float*)d_out;   // doubles as the agg buffer

    char* ws = (char*)d_ws;
    unsigned short* support = (unsigned short*)ws; ws += (size_t)NN * DD * 2;  // 12.8 MB bf16
    int2*  permA  = (int2*)ws;   ws += (size_t)NE * 8;        // 12.8 MB coarse-grouped
    int2*  perm   = (int2*)ws;   ws += (size_t)NE * 8;        // 12.8 MB per-node CSR
    int*   cnt98  = (int*)ws;    ws += NCOARSE * 4;
    float* ss     = (float*)ws;  ws += 128 * 4;               // scale|shift
    int*   cstart = (int*)ws;    ws += (NCOARSE + 1) * 4;
    int*   ctail  = (int*)ws;    ws += NCOARSE * 4;
    int*   bstart = (int*)ws;    ws += (NN + 4) * 4;          // per-node CSR offsets
    float* pstat  = (float*)ws;  ws += STAT_BLOCKS * 2 * DD * 4;  // 128 KB partials

    // zero cnt98 only (partials/ss fully overwritten each call)
    hipMemsetAsync(cnt98, 0, NCOARSE * 4, stream);

    k_gemm_hist<<<GEMM_GS + HIST_BLOCKS, 256, 0, stream>>>(x, W, support, edst, cnt98);
    k_scan98   <<<1, 128, 0, stream>>>(cnt98, cstart, ctail, bstart);
    k_placeA   <<<PLACE_BLOCKS, 256, 0, stream>>>(esrc, edst, ew, ctail, permA);
    k_placeB   <<<NCOARSE, 1024, 0, stream>>>(cstart, permA, perm, bstart);
    k_gather   <<<NN / 4, 256, 0, stream>>>(bstart, perm, (const unsigned*)support, out);
    k_stats    <<<STAT_BLOCKS, 256, 0, stream>>>(out, pstat);
    k_finstats <<<1, 128, 0, stream>>>(pstat, ss, gamma, beta);
    k_final    <<<NN * DD / 4 / 256, 256, 0, stream>>>(out, ss);
}

// Round 10
// 262.456 us; speedup vs baseline: 3.4267x; 1.1629x over previous
//
#include <hip/hip_runtime.h>
#include <hip/hip_bf16.h>

#define NN 100000
#define NE 1600000
#define DD 64
#define NCOARSE 98          // 1024-node coarse buckets (node>>10)
#define GEMM_TILES 1563     // ceil(NN/64); last tile has 32 rows
#define HIST_BLOCKS 125     // NE/12800
#define PLACE_EPB 8192
#define PLACE_BLOCKS 196    // ceil(NE/8192)
#define STAT_BLOCKS 256

__device__ inline unsigned short f2bf(float f) {
    __hip_bfloat16 h = __float2bfloat16(f);
    unsigned short s; __builtin_memcpy(&s, &h, 2); return s;
}

// ---------------- K1: fused  support_bf16 = x@W (LDS-tiled)  +  coarse dst histogram ----------------
// GEMM block: 64 rows. Wave = 16 rows as 2 half-waves x 8 rows; lane pair-cols (2hl,2hl+1).
// x tile staged in LDS (coalesced), rows broadcast-read from LDS; W col-pairs read b64.
__global__ __launch_bounds__(256) void k_gemm_hist(const float* __restrict__ x,
                                                   const float* __restrict__ Wg,
                                                   unsigned* __restrict__ support2,
                                                   const int* __restrict__ edst,
                                                   int* __restrict__ cnt98) {
    if (blockIdx.x >= GEMM_TILES) {
        __shared__ int h[NCOARSE];
        for (int i = threadIdx.x; i < NCOARSE; i += 256) h[i] = 0;
        __syncthreads();
        const int base = (blockIdx.x - GEMM_TILES) * 12800;
#pragma unroll 5
        for (int k = 0; k < 50; ++k)
            atomicAdd(&h[edst[base + k * 256 + threadIdx.x] >> 10], 1);
        __syncthreads();
        for (int i = threadIdx.x; i < NCOARSE; i += 256)
            if (h[i]) atomicAdd(&cnt98[i], h[i]);
        return;
    }

    __shared__ float Ws[DD * DD];   // 16 KB
    __shared__ float Xs[64 * DD];   // 16 KB
    const int r0 = blockIdx.x * 64;
    const int nrows = (r0 + 64 <= NN) ? 64 : (NN - r0);

    for (int i = threadIdx.x; i < DD * DD / 4; i += 256)
        ((float4*)Ws)[i] = ((const float4*)Wg)[i];
    const float4* xg = (const float4*)(x + (size_t)r0 * DD);
    for (int i = threadIdx.x; i < nrows * 16; i += 256)
        ((float4*)Xs)[i] = xg[i];
    __syncthreads();

    const int wave = threadIdx.x >> 6, lane = threadIdx.x & 63;
    const int half = lane >> 5, hl = lane & 31;
    const int rbase = wave * 16 + half * 8;   // first tile-row this lane accumulates

    float acc0[8] = {0.f, 0.f, 0.f, 0.f, 0.f, 0.f, 0.f, 0.f};
    float acc1[8] = {0.f, 0.f, 0.f, 0.f, 0.f, 0.f, 0.f, 0.f};
#pragma unroll 4
    for (int k = 0; k < DD; k += 4) {
        float2 w0 = *(const float2*)&Ws[(k + 0) * DD + 2 * hl];
        float2 w1 = *(const float2*)&Ws[(k + 1) * DD + 2 * hl];
        float2 w2 = *(const float2*)&Ws[(k + 2) * DD + 2 * hl];
        float2 w3 = *(const float2*)&Ws[(k + 3) * DD + 2 * hl];
#pragma unroll
        for (int r = 0; r < 8; ++r) {
            float4 xv = *(const float4*)&Xs[(rbase + r) * DD + k];
            acc0[r] = fmaf(xv.x, w0.x, acc0[r]); acc1[r] = fmaf(xv.x, w0.y, acc1[r]);
            acc0[r] = fmaf(xv.y, w1.x, acc0[r]); acc1[r] = fmaf(xv.y, w1.y, acc1[r]);
            acc0[r] = fmaf(xv.z, w2.x, acc0[r]); acc1[r] = fmaf(xv.z, w2.y, acc1[r]);
            acc0[r] = fmaf(xv.w, w3.x, acc0[r]); acc1[r] = fmaf(xv.w, w3.y, acc1[r]);
        }
    }
#pragma unroll
    for (int r = 0; r < 8; ++r) {
        const int row = rbase + r;
        if (row < nrows) {
            unsigned p = (unsigned)f2bf(acc0[r]) | ((unsigned)f2bf(acc1[r]) << 16);
            support2[(size_t)(r0 + row) * 32 + hl] = p;
        }
    }
}

// ---------------- K2: exclusive scan of 98 coarse counts ----------------
__global__ __launch_bounds__(128) void k_scan98(const int* __restrict__ cnt98,
                                                int* __restrict__ cstart,
                                                int* __restrict__ ctail,
                                                int* __restrict__ bstart) {
    __shared__ int sc[128];
    const int t = threadIdx.x;
    const int v = (t < NCOARSE) ? cnt98[t] : 0;
    sc[t] = v; __syncthreads();
    for (int o = 1; o < 128; o <<= 1) {
        int u = (t >= o) ? sc[t - o] : 0;
        __syncthreads();
        sc[t] += u;
        __syncthreads();
    }
    if (t < NCOARSE) { cstart[t] = sc[t] - v; ctail[t] = sc[t] - v; }
    if (t == 0) { cstart[NCOARSE] = NE; bstart[NN] = NE; }
}

// ---------------- K3: placeA — group edges by coarse bucket ----------------
// permA.x = src | (dlocal<<20)  (src<2^17, dlocal 10 bits);  permA.y = weight bits
__global__ __launch_bounds__(256) void k_placeA(const int* __restrict__ esrc,
                                                const int* __restrict__ edst,
                                                const float* __restrict__ ew,
                                                int* __restrict__ ctail,
                                                int2* __restrict__ permA) {
    __shared__ int lcnt[NCOARSE], loff[NCOARSE];
    for (int i = threadIdx.x; i < NCOARSE; i += 256) lcnt[i] = 0;
    __syncthreads();
    const int e0 = blockIdx.x * PLACE_EPB;
#pragma unroll 4
    for (int k = 0; k < 32; ++k) {
        int e = e0 + k * 256 + threadIdx.x;
        if (e < NE) atomicAdd(&lcnt[edst[e] >> 10], 1);
    }
    __syncthreads();
    for (int i = threadIdx.x; i < NCOARSE; i += 256) {
        int c = lcnt[i];
        loff[i] = c ? atomicAdd(&ctail[i], c) : 0;
    }
    __syncthreads();
#pragma unroll 4
    for (int k = 0; k < 32; ++k) {
        int e = e0 + k * 256 + threadIdx.x;
        if (e < NE) {
            int d = edst[e];
            int p = atomicAdd(&loff[d >> 10], 1);
            permA[p] = make_int2(esrc[e] | ((d & 1023) << 20), __float_as_int(ew[e]));
        }
    }
}

// ---------------- K4: placeB — exact per-node CSR within each coarse bucket ----------------
__global__ __launch_bounds__(1024) void k_placeB(const int* __restrict__ cstart,
                                                 const int2* __restrict__ permA,
                                                 int2* __restrict__ perm,
                                                 int* __restrict__ bstart) {
    __shared__ int sc[1024], loff[1024];
    const int c = blockIdx.x, t = threadIdx.x;
    const int cs = cstart[c], ce = cstart[c + 1];
    sc[t] = 0;
    __syncthreads();
    for (int j = cs + t; j < ce; j += 1024)
        atomicAdd(&sc[(permA[j].x >> 20) & 1023], 1);
    __syncthreads();
    const int cnt = sc[t];
    for (int o = 1; o < 1024; o <<= 1) {
        int u = (t >= o) ? sc[t - o] : 0;
        __syncthreads();
        sc[t] += u;
        __syncthreads();
    }
    const int base = cs + sc[t] - cnt;
    loff[t] = base;
    const int node = c * 1024 + t;
    if (node < NN) bstart[node] = base;
    __syncthreads();
    for (int j = cs + t; j < ce; j += 1024) {
        int2 m = permA[j];
        int p = atomicAdd(&loff[(m.x >> 20) & 1023], 1);
        perm[p] = make_int2(m.x & 0xFFFFF, m.y);
    }
}

// ---------------- K5: gather — one wave per node, register accumulate, dword bf16 loads ----------------
__global__ __launch_bounds__(256) void k_gather(const int* __restrict__ bstart,
                                                const int2* __restrict__ perm,
                                                const unsigned* __restrict__ support2,
                                                float* __restrict__ out) {
    const int wave = threadIdx.x >> 6, lane = threadIdx.x & 63;
    const int half = lane >> 5, hl = lane & 31;
    const int d = blockIdx.x * 4 + wave;            // grid = NN/4 exactly
    const int bs = bstart[d], be = bstart[d + 1];
    float ax = 0.f, ay = 0.f, bx = 0.f, by = 0.f;
    int j0 = bs;
    for (; j0 + 3 < be; j0 += 4) {
        int2 mA = perm[j0 + half];
        int2 mB = perm[j0 + 2 + half];
        unsigned pA = support2[(size_t)mA.x * 32 + hl];
        unsigned pB = support2[(size_t)mB.x * 32 + hl];
        float wA = __int_as_float(mA.y), wB = __int_as_float(mB.y);
        ax = fmaf(wA, __uint_as_float(pA << 16), ax);
        ay = fmaf(wA, __uint_as_float(pA & 0xffff0000u), ay);
        bx = fmaf(wB, __uint_as_float(pB << 16), bx);
        by = fmaf(wB, __uint_as_float(pB & 0xffff0000u), by);
    }
    for (; j0 + half < be; j0 += 2) {
        int2 m = perm[j0 + half];
        unsigned p = support2[(size_t)m.x * 32 + hl];
        float w = __int_as_float(m.y);
        ax = fmaf(w, __uint_as_float(p << 16), ax);
        ay = fmaf(w, __uint_as_float(p & 0xffff0000u), ay);
    }
    ax += bx; ay += by;
    ax += __shfl_xor(ax, 32);
    ay += __shfl_xor(ay, 32);
    if (half == 0)
        *(float2*)(out + (size_t)d * DD + 2 * hl) = make_float2(ax, ay);
}

// ---------------- K6: per-column sum & sumsq -> per-block partials (NO atomics) ----------------
__device__ inline float4 shfl_down4(float4 v, int dd) {
    v.x = __shfl_down(v.x, dd, 64); v.y = __shfl_down(v.y, dd, 64);
    v.z = __shfl_down(v.z, dd, 64); v.w = __shfl_down(v.w, dd, 64);
    return v;
}
__device__ inline float4 add4(float4 a, float4 b) {
    a.x += b.x; a.y += b.y; a.z += b.z; a.w += b.w; return a;
}

__global__ __launch_bounds__(256) void k_stats(const float* __restrict__ agg,
                                               float* __restrict__ pstat) {
    const int lane = threadIdx.x & 63, wave = threadIdx.x >> 6;
    const int q = lane & 15, sub = lane >> 4;
    float4 s = {0, 0, 0, 0}, sq = {0, 0, 0, 0};
    const int stride = gridDim.x * 16;
    for (int row = (blockIdx.x * 4 + wave) * 4 + sub; row < NN; row += stride) {
        float4 v = *(const float4*)(agg + (size_t)row * DD + q * 4);
        s.x += v.x; s.y += v.y; s.z += v.z; s.w += v.w;
        sq.x = fmaf(v.x, v.x, sq.x); sq.y = fmaf(v.y, v.y, sq.y);
        sq.z = fmaf(v.z, v.z, sq.z); sq.w = fmaf(v.w, v.w, sq.w);
    }
    s = add4(s, shfl_down4(s, 32));  s = add4(s, shfl_down4(s, 16));
    sq = add4(sq, shfl_down4(sq, 32)); sq = add4(sq, shfl_down4(sq, 16));

    __shared__ float red[2][4][DD];
    if (lane < 16) {
        red[0][wave][q * 4 + 0] = s.x;  red[0][wave][q * 4 + 1] = s.y;
        red[0][wave][q * 4 + 2] = s.z;  red[0][wave][q * 4 + 3] = s.w;
        red[1][wave][q * 4 + 0] = sq.x; red[1][wave][q * 4 + 1] = sq.y;
        red[1][wave][q * 4 + 2] = sq.z; red[1][wave][q * 4 + 3] = sq.w;
    }
    __syncthreads();
    if (threadIdx.x < 2 * DD) {
        const int t = threadIdx.x;           // 0..63 = sum, 64..127 = sumsq
        const int part = t >> 6, c = t & 63;
        pstat[blockIdx.x * 2 * DD + t] =
            red[part][0][c] + red[part][1][c] + red[part][2][c] + red[part][3][c];
    }
}

// ---------------- K7: reduce partials + fold into scale/shift ----------------
__global__ __launch_bounds__(128) void k_finstats(const float* __restrict__ pstat,
                                                  float* __restrict__ ss,
                                                  const float* __restrict__ gamma,
                                                  const float* __restrict__ beta) {
    const int t = threadIdx.x;               // 0..127
    float acc = 0.f;
    for (int b = 0; b < STAT_BLOCKS; ++b)
        acc += pstat[b * 2 * DD + t];
    __shared__ float red[2 * DD];
    red[t] = acc;
    __syncthreads();
    if (t < DD) {
        const float invn = 1.0f / NN;
        float mean = red[t] * invn;
        float var = fmaxf(red[DD + t] * invn - mean * mean, 0.f);
        float sc = rsqrtf(var + 1e-5f) * gamma[t];
        ss[t] = sc;
        ss[DD + t] = beta[t] - mean * sc;
    }
}

// ---------------- K8: out = relu(out*scale + shift) in-place ----------------
__global__ __launch_bounds__(256) void k_final(float* __restrict__ out,
                                               const float* __restrict__ ss) {
    const size_t idx = ((size_t)blockIdx.x * 256 + threadIdx.x) * 4;
    const int c = (int)(idx & 63);
    float4 v = *(const float4*)(out + idx);
    float4 o;
    o.x = fmaxf(fmaf(v.x, ss[c + 0], ss[DD + c + 0]), 0.f);
    o.y = fmaxf(fmaf(v.y, ss[c + 1], ss[DD + c + 1]), 0.f);
    o.z = fmaxf(fmaf(v.z, ss[c + 2], ss[DD + c + 2]), 0.f);
    o.w = fmaxf(fmaf(v.w, ss[c + 3], ss[DD + c + 3]), 0.f);
    *(float4*)(out + idx) = o;
}

extern "C" void kernel_launch(void* const* d_in, const int* in_sizes, int n_in,
                              void* d_out, int out_size, void* d_ws, size_t ws_size,
                              hipStream_t stream) {
    const float* x     = (const float*)d_in[0];
    const int*   esrc  = (const int*)d_in[1];
    const int*   edst  = (const int*)d_in[2];
    const float* ew    = (const float*)d_in[3];
    const float* W     = (const float*)d_in[4];
    // d_in[5] = bias: cancels exactly in batchnorm (shift-invariant) — unused.
    const float* gamma = (const float*)d_in[6];
    const float* beta  = (const float*)d_in[7];
    float*       out   = (float*)d_out;   // doubles as the agg buffer

    char* ws = (char*)d_ws;
    unsigned* support2 = (unsigned*)ws;  ws += (size_t)NN * DD * 2;  // 12.8 MB bf16 (dword-packed)
    int2*  permA  = (int2*)ws;   ws += (size_t)NE * 8;        // 12.8 MB coarse-grouped
    int2*  perm   = (int2*)ws;   ws += (size_t)NE * 8;        // 12.8 MB per-node CSR
    int*   cnt98  = (int*)ws;    ws += NCOARSE * 4;
    float* ss     = (float*)ws;  ws += 128 * 4;               // scale|shift
    int*   cstart = (int*)ws;    ws += (NCOARSE + 1) * 4;
    int*   ctail  = (int*)ws;    ws += NCOARSE * 4;
    int*   bstart = (int*)ws;    ws += (NN + 4) * 4;          // per-node CSR offsets
    float* pstat  = (float*)ws;  ws += STAT_BLOCKS * 2 * DD * 4;  // 128 KB partials

    // zero cnt98 only (partials/ss fully overwritten each call)
    hipMemsetAsync(cnt98, 0, NCOARSE * 4, stream);

    k_gemm_hist<<<GEMM_TILES + HIST_BLOCKS, 256, 0, stream>>>(x, W, support2, edst, cnt98);
    k_scan98   <<<1, 128, 0, stream>>>(cnt98, cstart, ctail, bstart);
    k_placeA   <<<PLACE_BLOCKS, 256, 0, stream>>>(esrc, edst, ew, ctail, permA);
    k_placeB   <<<NCOARSE, 1024, 0, stream>>>(cstart, permA, perm, bstart);
    k_gather   <<<NN / 4, 256, 0, stream>>>(bstart, perm, support2, out);
    k_stats    <<<STAT_BLOCKS, 256, 0, stream>>>(out, pstat);
    k_finstats <<<1, 128, 0, stream>>>(pstat, ss, gamma, beta);
    k_final    <<<NN * DD / 4 / 256, 256, 0, stream>>>(out, ss);
}